// Round 15
// baseline (3228.575 us; speedup 1.0000x reference)
//
#include <hip/hip_runtime.h>
#include <hip/hip_bf16.h>

// SentenceClassifier: LSTM(B=64,T=512,E=512,H=1024) -> h_T @ outW + outb -> softmax/CE
// Persistent-kernel, 128 worker blocks x 256 thr. R15: DIRECT POLL (aggregator
// removed). R14's detect chain ran flag -> aggregator poll -> epoch replica ->
// consumer poll = ~4 LLC hops; consumers now watch the 128 producer flags of
// their wave-plane directly (2 padded slots/lane, s_sleep(1) backoff) = 2 hops.
// The poll-storm concern that motivated the aggregator (R11) was falsified by
// R11/R12 nulls. Everything else R14-verbatim: rotating cold h buffers
// (block-major [bc][row][8hid]); agent write-through 8B h-stores inline in the
// cell r-loop; counted store-ack (vmcnt(16)) overlapped with t+1 x-loads;
// 4-phase h-burst drain (vmcnt 24/16/8/0, 8 MFMAs each) with relaxed
// sched_barrier(0x187) (ALU|VALU|SALU|DS may cross; MFMA+VMEM pinned);
// x-part W in registers; x-GEMM in the detect shadow; no __syncthreads in
// the t-loop. kk order unchanged -- bit-identical numerics (absmax 0.125).

#define Bb 64
#define Tt 512
#define Ee 512
#define Hh 1024
#define Cc 32
#define G4 4096
#define NKS 48     // (E+H)/32
#define NBLK 128
#define HIDB 8     // hid units per block
#define FPAD 32    // flag slot pad (ints) = 128B

typedef __attribute__((ext_vector_type(8))) short short8;
typedef __attribute__((ext_vector_type(4))) float f32x4;

__device__ __forceinline__ unsigned short f2bf(float f) {
  __hip_bfloat16 h = __float2bfloat16(f);
  union { __hip_bfloat16 h; unsigned short u; } cv; cv.h = h; return cv.u;
}
static __device__ __forceinline__ float fsig(float x) { return 1.0f / (1.0f + __expf(-x)); }
static __device__ __forceinline__ float ftanhf(float x) {
  float e = __expf(-2.0f * fabsf(x));
  float t = (1.0f - e) / (1.0f + e);
  return copysignf(t, x);
}

// ---- x [B,T,E] f32 -> xT [T,B,E] bf16 (contiguous 64KB window per step) ----
__global__ __launch_bounds__(256) void transpose_x_kernel(const float* __restrict__ x,
                                                          unsigned short* __restrict__ xT) {
  const int bid = blockIdx.x;          // row*Tt + t
  const int row = bid >> 9, t = bid & (Tt - 1);
  const int e = threadIdx.x * 2;
  const float* src = x + ((size_t)row * Tt + t) * Ee + e;
  float2 v = *(const float2*)src;
  ushort2 o; o.x = f2bf(v.x); o.y = f2bf(v.y);
  *(ushort2*)(xT + ((size_t)t * Bb + row) * Ee + e) = o;
}

// ---- W [1536,4096] f32 -> per-block B-frag-packed bf16 --------------------
__global__ __launch_bounds__(64) void pack_w_kernel(const float* __restrict__ W,
                                                    unsigned short* __restrict__ Wpk) {
  const int fid = blockIdx.x;          // blk*96 + tau*48 + ks
  const int l = threadIdx.x;
  const int blk = fid / 96, rem = fid % 96;
  const int tau = rem / 48, ks = rem % 48;
  const int c = l & 15;
  const int col = (2 * tau + (c >> 3)) * Hh + blk * HIDB + (c & 7);
  const int k0 = ks * 32 + (l >> 4) * 8;
  short8 v;
#pragma unroll
  for (int i = 0; i < 8; i++) v[i] = (short)f2bf(W[(size_t)(k0 + i) * G4 + col]);
  *(short8*)(Wpk + ((size_t)fid * 64 + l) * 8) = v;
}

// ---- zero h buffer 0 + flag state -----------------------------------------
__global__ __launch_bounds__(256) void init_state_kernel(unsigned short* __restrict__ h0,
                                                         int* __restrict__ flg) {
  int i = blockIdx.x * 256 + threadIdx.x;   // grid covers Bb*Hh
  h0[i] = 0;
  if (i < 4 * NBLK * FPAD) flg[i] = 0;      // 512 padded flag slots
}

// ---- persistent LSTM kernel ----------------------------------------------
__global__ __launch_bounds__(256, 1) void lstm_persist(
    const unsigned short* __restrict__ xT, const unsigned short* __restrict__ Wpk,
    const float* __restrict__ bias,
    unsigned short* __restrict__ hseq,   // Tt buffers, block-major [bc][row][8hid]
    float* __restrict__ h_f32, int* __restrict__ flg) {
  const int bc = blockIdx.x;
  const int tid = threadIdx.x;
  const int wv = tid >> 6, ln = tid & 63;

  __shared__ short8 Wl[2 * NKS * 64];       // 96 KiB

  { // one-time: W slice -> LDS (linear 96KB copy)
    const short8* src = (const short8*)Wpk + (size_t)bc * (2 * NKS * 64);
    for (int i = tid; i < 2 * NKS * 64; i += 256) Wl[i] = src[i];
  }

  const int c = ln & 15, kg = ln >> 4;
  const int arow = wv * 16 + c;        // A-frag row = batch index
  const int rbase = wv * 16 + kg * 4;  // D rows (m89 layout: row=(l>>4)*4+r, col=l&15)
  const int hid = bc * HIDB + (c & 7);
  const bool lo = (c < 8);
  const float bi = bias[hid], bj = bias[Hh + hid];
  const float bff = bias[2 * Hh + hid], bo = bias[3 * Hh + hid];
  float cstate[4] = {0.f, 0.f, 0.f, 0.f};

  __syncthreads();                      // W in LDS ready (only barrier in kernel)

  const short8* W0 = Wl;                // tile0 (gates i,j)
  const short8* W1 = Wl + NKS * 64;     // tile1 (gates f,o)

  // x-part W fragments: same LDS addresses every step -> hoist to registers
  short8 wx0[16], wx1[16];
#pragma unroll
  for (int kk = 0; kk < 16; kk++) { wx0[kk] = W0[kk * 64 + ln]; wx1[kk] = W1[kk * 64 + ln]; }

  int* flgw = flg + wv * NBLK * FPAD;   // own wave's flag domain
  int* myslot = flgw + bc * FPAD;
  int* slot0 = flgw + ln * FPAD;        // direct wait-all: 2 slots per lane
  int* slot1 = flgw + (ln + 64) * FPAD;

  f32x4 xa0, xa1;
  // x-part for t=0
  {
    const unsigned short* xr = xT + ((size_t)0 * Bb + arow) * Ee + kg * 8;
    f32x4 a0 = {0.f,0.f,0.f,0.f}, a1 = {0.f,0.f,0.f,0.f};
#pragma unroll
    for (int kk = 0; kk < 16; kk++) {
      short8 a = *(const short8*)(xr + kk * 32);
      a0 = __builtin_amdgcn_mfma_f32_16x16x32_bf16(a, wx0[kk], a0, 0, 0, 0);
      a1 = __builtin_amdgcn_mfma_f32_16x16x32_bf16(a, wx1[kk], a1, 0, 0, 0);
    }
    xa0 = a0; xa1 = a1;
  }

  for (int t = 0; t < Tt; t++) {
    // ---- direct detect: own wave-plane's 128 producer flags, 2 slots/lane.
    // Chain: producer flag store -> this poll (2 LLC hops total vs R14's 4).
    for (;;) {
      int v0 = __hip_atomic_load(slot0, __ATOMIC_RELAXED, __HIP_MEMORY_SCOPE_AGENT);
      int v1 = __hip_atomic_load(slot1, __ATOMIC_RELAXED, __HIP_MEMORY_SCOPE_AGENT);
      if (v0 >= t && v1 >= t) break;
      __builtin_amdgcn_s_sleep(1);
    }
    asm volatile("" ::: "memory");      // no hoist of h loads above the wait

    // ---- forced burst, 4-phase drain: issue all 32 16B loads; MFMA 8 at a
    // time as loads retire (in-order). sched_barrier(0x187) lets W_h ds_reads
    // + address ALU float into the load-wait windows; MFMA+VMEM stay pinned.
    const unsigned short* hr = hseq + (size_t)t * (NBLK * Bb * HIDB) + kg * 512 + arow * 8;
    short8 f[32];
#pragma unroll
    for (int kk = 0; kk < 32; kk++) f[kk] = *(const short8*)(hr + kk * 2048);

    f32x4 a0 = xa0, a1 = xa1;
    asm volatile("s_waitcnt vmcnt(24)" ::: "memory");   // f[0..7] landed
    __builtin_amdgcn_sched_barrier(0x187);
#pragma unroll
    for (int kk = 0; kk < 8; kk++) {
      a0 = __builtin_amdgcn_mfma_f32_16x16x32_bf16(f[kk], W0[(16 + kk) * 64 + ln], a0, 0, 0, 0);
      a1 = __builtin_amdgcn_mfma_f32_16x16x32_bf16(f[kk], W1[(16 + kk) * 64 + ln], a1, 0, 0, 0);
    }
    asm volatile("s_waitcnt vmcnt(16)" ::: "memory");   // f[8..15]
    __builtin_amdgcn_sched_barrier(0x187);
#pragma unroll
    for (int kk = 8; kk < 16; kk++) {
      a0 = __builtin_amdgcn_mfma_f32_16x16x32_bf16(f[kk], W0[(16 + kk) * 64 + ln], a0, 0, 0, 0);
      a1 = __builtin_amdgcn_mfma_f32_16x16x32_bf16(f[kk], W1[(16 + kk) * 64 + ln], a1, 0, 0, 0);
    }
    asm volatile("s_waitcnt vmcnt(8)" ::: "memory");    // f[16..23]
    __builtin_amdgcn_sched_barrier(0x187);
#pragma unroll
    for (int kk = 16; kk < 24; kk++) {
      a0 = __builtin_amdgcn_mfma_f32_16x16x32_bf16(f[kk], W0[(16 + kk) * 64 + ln], a0, 0, 0, 0);
      a1 = __builtin_amdgcn_mfma_f32_16x16x32_bf16(f[kk], W1[(16 + kk) * 64 + ln], a1, 0, 0, 0);
    }
    asm volatile("s_waitcnt vmcnt(0)" ::: "memory");    // f[24..31]
    __builtin_amdgcn_sched_barrier(0x187);
#pragma unroll
    for (int kk = 24; kk < 32; kk++) {
      a0 = __builtin_amdgcn_mfma_f32_16x16x32_bf16(f[kk], W0[(16 + kk) * 64 + ln], a0, 0, 0, 0);
      a1 = __builtin_amdgcn_mfma_f32_16x16x32_bf16(f[kk], W1[(16 + kk) * 64 + ln], a1, 0, 0, 0);
    }

    if (t < Tt - 1) {
      // ---- cell update with INLINE pack+store: store for row-group r flies
      // while r+1's transcendental chain computes. vmcnt clean at entry
      // (burst fully drained above) -> exactly 4 store instrs outstanding.
      unsigned long long* hob = (unsigned long long*)hseq
                                + (size_t)(t + 1) * (NBLK * Bb * HIDB / 4)
                                + bc * (Bb * HIDB / 4);
#pragma unroll
      for (int r = 0; r < 4; r++) {
        const float p0 = a0[r], p1 = a1[r];
        const float s0 = __shfl_xor(p0, 8), s1 = __shfl_xor(p1, 8);
        const float gi = (lo ? p0 : s0) + bi;
        const float gj = (lo ? s0 : p0) + bj;
        const float gf = (lo ? p1 : s1) + bff;
        const float go = (lo ? s1 : p1) + bo;
        const float cn = cstate[r] * fsig(gf + 1.0f) + fsig(gi) * ftanhf(gj);
        cstate[r] = cn;
        const float hn = ftanhf(cn) * fsig(go);
        unsigned short us = f2bf(hn);
        unsigned short ps = (unsigned short)__shfl_xor((int)us, 1);
        unsigned int hw = (unsigned)us | ((unsigned)ps << 16);
        unsigned int p2 = (unsigned)__shfl_xor((int)hw, 2);
        unsigned long long hq = (unsigned long long)hw | ((unsigned long long)p2 << 32);
        if (lo && !(c & 3))
          __hip_atomic_store(hob + (rbase + r) * 2 + (c >> 2),
                             hq, __ATOMIC_RELAXED, __HIP_MEMORY_SCOPE_AGENT);
      }
      asm volatile("" ::: "memory");    // stores issued above this point
      // ---- x-loads for t+1 issued BEFORE the ack; counted drain acks only
      // the 4 stores (oldest), x-loads keep flying under the flag + x-GEMM.
      const unsigned short* xr = xT + ((size_t)(t + 1) * Bb + arow) * Ee + kg * 8;
      short8 xl[16];
#pragma unroll
      for (int kk = 0; kk < 16; kk++) xl[kk] = *(const short8*)(xr + kk * 32);
      asm volatile("s_waitcnt vmcnt(16)" ::: "memory"); // 4 stores acked
      __builtin_amdgcn_sched_barrier(0x187);
      if (ln == 0)
        __hip_atomic_store(myslot, t + 1, __ATOMIC_RELAXED, __HIP_MEMORY_SCOPE_AGENT);
      // x-part MFMAs for t+1 (W from registers) in the detect shadow
      {
        f32x4 b0 = {0.f,0.f,0.f,0.f}, b1 = {0.f,0.f,0.f,0.f};
#pragma unroll
        for (int kk = 0; kk < 16; kk++) {
          b0 = __builtin_amdgcn_mfma_f32_16x16x32_bf16(xl[kk], wx0[kk], b0, 0, 0, 0);
          b1 = __builtin_amdgcn_mfma_f32_16x16x32_bf16(xl[kk], wx1[kk], b1, 0, 0, 0);
        }
        xa0 = b0; xa1 = b1;
      }
    } else {
      float hnew[4];
#pragma unroll
      for (int r = 0; r < 4; r++) {
        const float p0 = a0[r], p1 = a1[r];
        const float s0 = __shfl_xor(p0, 8), s1 = __shfl_xor(p1, 8);
        const float gi = (lo ? p0 : s0) + bi;
        const float gj = (lo ? s0 : p0) + bj;
        const float gf = (lo ? p1 : s1) + bff;
        const float go = (lo ? s1 : p1) + bo;
        const float cn = cstate[r] * fsig(gf + 1.0f) + fsig(gi) * ftanhf(gj);
        cstate[r] = cn;
        hnew[r] = ftanhf(cn) * fsig(go);
      }
      if (lo) {
#pragma unroll
        for (int r = 0; r < 4; r++) h_f32[(rbase + r) * Hh + hid] = hnew[r];
      }
    }
  }
}

// ---- classifier: pred = h @ outW + outb, softmax, per-row CE --------------
__global__ __launch_bounds__(256) void classifier_kernel(
    const float* __restrict__ h, const float* __restrict__ outW,
    const float* __restrict__ outb, const float* __restrict__ y,
    float* __restrict__ out, float* __restrict__ losses) {
  __shared__ float red[256];
  const int brow = blockIdx.x;
  const int tid = threadIdx.x;
  const int cc = tid & 31;
  const int part = tid >> 5;
  const float* hr = h + brow * Hh;
  float p = 0.f;
  for (int k = part * 128; k < part * 128 + 128; k++)
    p += hr[k] * outW[k * Cc + cc];
  red[tid] = p;
  __syncthreads();
  if (part < 4) red[tid] += red[tid + 128];
  __syncthreads();
  if (part < 2) red[tid] += red[tid + 64];
  __syncthreads();
  if (part < 1) red[tid] += red[tid + 32];
  __syncthreads();
  if (tid < 32) {
    const float logit = red[tid] + outb[tid];
    float m = logit;
    for (int off = 16; off >= 1; off >>= 1) m = fmaxf(m, __shfl_xor(m, off));
    const float e = __expf(logit - m);
    float s = e;
    for (int off = 16; off >= 1; off >>= 1) s += __shfl_xor(s, off);
    out[brow * Cc + tid] = logit;
    out[Bb * Cc + brow * Cc + tid] = e / s;
    const float logp = (logit - m) - __logf(s);
    float contrib = y[brow * Cc + tid] * logp;
    for (int off = 16; off >= 1; off >>= 1) contrib += __shfl_xor(contrib, off);
    if (tid == 0) losses[brow] = -contrib;
  }
}

__global__ __launch_bounds__(64) void finalize_kernel(const float* __restrict__ losses,
                                                      float* __restrict__ out) {
  float v = losses[threadIdx.x];
  for (int off = 32; off >= 1; off >>= 1) v += __shfl_down(v, off);
  if (threadIdx.x == 0) out[2 * Bb * Cc] = v * (1.0f / Bb);
}

extern "C" void kernel_launch(void* const* d_in, const int* in_sizes, int n_in,
                              void* d_out, int out_size, void* d_ws, size_t ws_size,
                              hipStream_t stream) {
  const float* x    = (const float*)d_in[0];
  const float* y    = (const float*)d_in[1];
  // d_in[2] = seqlen (unused)
  const float* W    = (const float*)d_in[3];
  const float* bias = (const float*)d_in[4];
  const float* outW = (const float*)d_in[5];
  const float* outb = (const float*)d_in[6];
  float* out = (float*)d_out;

  char* wsp = (char*)d_ws;
  size_t off = 0;
  auto walloc = [&](size_t bytes) -> void* {
    void* p = wsp + off;
    off += (bytes + 255) & ~(size_t)255;
    return p;
  };
  unsigned short* xT   = (unsigned short*)walloc((size_t)Bb * Tt * Ee * 2);         // 32 MiB
  unsigned short* Wpk  = (unsigned short*)walloc((size_t)NBLK * 2 * NKS * 64 * 16); // 12 MiB
  unsigned short* hseq = (unsigned short*)walloc((size_t)Tt * Bb * Hh * 2);         // 64 MiB rotating h
  float* hf     = (float*)walloc((size_t)Bb * Hh * 4);
  float* losses = (float*)walloc(256);
  int* flg      = (int*)walloc(4 * NBLK * FPAD * 4);                                // 64 KiB flags
  (void)ws_size; (void)in_sizes; (void)n_in; (void)out_size;

  transpose_x_kernel<<<Bb * Tt, 256, 0, stream>>>(x, xT);
  pack_w_kernel<<<NBLK * 2 * NKS, 64, 0, stream>>>(W, Wpk);
  init_state_kernel<<<(Bb * Hh) / 256, 256, 0, stream>>>(hseq, flg);

  lstm_persist<<<NBLK, 256, 0, stream>>>(xT, Wpk, bias, hseq, hf, flg);

  classifier_kernel<<<Bb, 256, 0, stream>>>(hf, outW, outb, y, out, losses);
  finalize_kernel<<<1, 64, 0, stream>>>(losses, out);
}

// Round 16
// 2716.815 us; speedup vs baseline: 1.1884x; 1.1884x over previous
//
#include <hip/hip_runtime.h>
#include <hip/hip_bf16.h>

// SentenceClassifier: LSTM(B=64,T=512,E=512,H=1024) -> h_T @ outW + outb -> softmax/CE
// Persistent-kernel, 128 worker blocks x 256 thr + 2 AGGREGATOR blocks.
// R16 = R14 (best, 3019us) + two residual-latency levers:
//  (a) DUAL AGGREGATORS sampling at independent phases: agg a writes replica
//      lines [8a,8a+8) per plane; consumers poll one replica from EACH set and
//      proceed when either >= t (both aggs publish only after a full min-scan,
//      so either is sufficient). Cuts ~half an aggregator poll period (~0.2us)
//      off the detect path. (R15 showed direct poll regresses: storm > hops.)
//  (b) SPLIT ACCUMULATORS: a0/a1 each split into two 16-deep dependent MFMA
//      chains (b0/b1 start at zero, summed at the end) -- doubles chain ILP.
//      Reorders two fp32 adds (absmax may move in LSBs).
// Everything else R14-verbatim: rotating cold h buffers (block-major
// [bc][row][8hid]); agent write-through 8B h-stores inline in the cell r-loop;
// counted store-ack (vmcnt(16)) overlapped with t+1 x-loads; 4-phase h-burst
// drain (vmcnt 24/16/8/0) with sched_barrier(0x187); x-part W in registers;
// x-GEMM in the detect shadow; no __syncthreads in the t-loop.

#define Bb 64
#define Tt 512
#define Ee 512
#define Hh 1024
#define Cc 32
#define G4 4096
#define NKS 48     // (E+H)/32
#define NBLK 128
#define HIDB 8     // hid units per block
#define FPAD 32    // flag slot pad (ints) = 128B
#define NREP 16    // epoch replicas per plane (8 per aggregator)

typedef __attribute__((ext_vector_type(8))) short short8;
typedef __attribute__((ext_vector_type(4))) float f32x4;

__device__ __forceinline__ unsigned short f2bf(float f) {
  __hip_bfloat16 h = __float2bfloat16(f);
  union { __hip_bfloat16 h; unsigned short u; } cv; cv.h = h; return cv.u;
}
static __device__ __forceinline__ float fsig(float x) { return 1.0f / (1.0f + __expf(-x)); }
static __device__ __forceinline__ float ftanhf(float x) {
  float e = __expf(-2.0f * fabsf(x));
  float t = (1.0f - e) / (1.0f + e);
  return copysignf(t, x);
}

// ---- x [B,T,E] f32 -> xT [T,B,E] bf16 (contiguous 64KB window per step) ----
__global__ __launch_bounds__(256) void transpose_x_kernel(const float* __restrict__ x,
                                                          unsigned short* __restrict__ xT) {
  const int bid = blockIdx.x;          // row*Tt + t
  const int row = bid >> 9, t = bid & (Tt - 1);
  const int e = threadIdx.x * 2;
  const float* src = x + ((size_t)row * Tt + t) * Ee + e;
  float2 v = *(const float2*)src;
  ushort2 o; o.x = f2bf(v.x); o.y = f2bf(v.y);
  *(ushort2*)(xT + ((size_t)t * Bb + row) * Ee + e) = o;
}

// ---- W [1536,4096] f32 -> per-block B-frag-packed bf16 --------------------
__global__ __launch_bounds__(64) void pack_w_kernel(const float* __restrict__ W,
                                                    unsigned short* __restrict__ Wpk) {
  const int fid = blockIdx.x;          // blk*96 + tau*48 + ks
  const int l = threadIdx.x;
  const int blk = fid / 96, rem = fid % 96;
  const int tau = rem / 48, ks = rem % 48;
  const int c = l & 15;
  const int col = (2 * tau + (c >> 3)) * Hh + blk * HIDB + (c & 7);
  const int k0 = ks * 32 + (l >> 4) * 8;
  short8 v;
#pragma unroll
  for (int i = 0; i < 8; i++) v[i] = (short)f2bf(W[(size_t)(k0 + i) * G4 + col]);
  *(short8*)(Wpk + ((size_t)fid * 64 + l) * 8) = v;
}

// ---- zero h buffer 0 + flag/epoch state -----------------------------------
__global__ __launch_bounds__(256) void init_state_kernel(unsigned short* __restrict__ h0,
                                                         int* __restrict__ flg) {
  int i = blockIdx.x * 256 + threadIdx.x;   // grid covers Bb*Hh
  h0[i] = 0;
  if (i < 4 * NBLK * FPAD + 4 * NREP * FPAD) flg[i] = 0;  // flags + epoch replicas
}

// ---- persistent LSTM kernel (+ 2 aggregator blocks) -----------------------
__global__ __launch_bounds__(256, 1) void lstm_persist(
    const unsigned short* __restrict__ xT, const unsigned short* __restrict__ Wpk,
    const float* __restrict__ bias,
    unsigned short* __restrict__ hseq,   // Tt buffers, block-major [bc][row][8hid]
    float* __restrict__ h_f32, int* __restrict__ flg) {
  const int bc = blockIdx.x;
  const int tid = threadIdx.x;
  const int wv = tid >> 6, ln = tid & 63;

  int* epoch = flg + 4 * NBLK * FPAD;   // 4 planes x 16 replica lines

  // ------- aggregator blocks (2): min-reduce flags -> replica halves -------
  if (bc >= NBLK) {
    const int ag = bc - NBLK;           // 0 or 1
    int* flgw2 = flg + wv * NBLK * FPAD;
    int* ep = epoch + (wv * NREP + ag * 8) * FPAD;
    int cur = 0;
    while (cur < Tt - 1) {
      int a = __hip_atomic_load(flgw2 + ln * FPAD,        __ATOMIC_RELAXED, __HIP_MEMORY_SCOPE_AGENT);
      int b = __hip_atomic_load(flgw2 + (ln + 64) * FPAD, __ATOMIC_RELAXED, __HIP_MEMORY_SCOPE_AGENT);
      int m = a < b ? a : b;
#pragma unroll
      for (int off = 32; off >= 1; off >>= 1) {
        int o = __shfl_xor(m, off);
        m = o < m ? o : m;
      }
      if (m > cur) {
        cur = m;
        if (ln < 8)                     // 8 replica stores in parallel
          __hip_atomic_store(ep + ln * FPAD, cur, __ATOMIC_RELAXED, __HIP_MEMORY_SCOPE_AGENT);
      }
    }
    return;
  }

  // ---------------- worker blocks ------------------------------------------
  __shared__ short8 Wl[2 * NKS * 64];       // 96 KiB

  { // one-time: W slice -> LDS (linear 96KB copy)
    const short8* src = (const short8*)Wpk + (size_t)bc * (2 * NKS * 64);
    for (int i = tid; i < 2 * NKS * 64; i += 256) Wl[i] = src[i];
  }

  const int c = ln & 15, kg = ln >> 4;
  const int arow = wv * 16 + c;        // A-frag row = batch index
  const int rbase = wv * 16 + kg * 4;  // D rows (m89 layout: row=(l>>4)*4+r, col=l&15)
  const int hid = bc * HIDB + (c & 7);
  const bool lo = (c < 8);
  const float bi = bias[hid], bj = bias[Hh + hid];
  const float bff = bias[2 * Hh + hid], bo = bias[3 * Hh + hid];
  float cstate[4] = {0.f, 0.f, 0.f, 0.f};

  __syncthreads();                      // W in LDS ready (only barrier in kernel)

  const short8* W0 = Wl;                // tile0 (gates i,j)
  const short8* W1 = Wl + NKS * 64;     // tile1 (gates f,o)

  // x-part W fragments: same LDS addresses every step -> hoist to registers
  short8 wx0[16], wx1[16];
#pragma unroll
  for (int kk = 0; kk < 16; kk++) { wx0[kk] = W0[kk * 64 + ln]; wx1[kk] = W1[kk * 64 + ln]; }

  int* flgw = flg + wv * NBLK * FPAD;   // own wave's flag domain
  int* myslot = flgw + bc * FPAD;
  // one replica from each aggregator's half; proceed when EITHER reaches t
  int* myep0 = epoch + (wv * NREP + (bc & 7)) * FPAD;
  int* myep1 = epoch + (wv * NREP + 8 + (bc & 7)) * FPAD;

  f32x4 xa0, xa1;
  // x-part for t=0
  {
    const unsigned short* xr = xT + ((size_t)0 * Bb + arow) * Ee + kg * 8;
    f32x4 a0 = {0.f,0.f,0.f,0.f}, a1 = {0.f,0.f,0.f,0.f};
#pragma unroll
    for (int kk = 0; kk < 16; kk++) {
      short8 a = *(const short8*)(xr + kk * 32);
      a0 = __builtin_amdgcn_mfma_f32_16x16x32_bf16(a, wx0[kk], a0, 0, 0, 0);
      a1 = __builtin_amdgcn_mfma_f32_16x16x32_bf16(a, wx1[kk], a1, 0, 0, 0);
    }
    xa0 = a0; xa1 = a1;
  }

  for (int t = 0; t < Tt; t++) {
    // ---- detect: either replica (dual aggregators sample out of phase)
    for (;;) {
      int e0 = __hip_atomic_load(myep0, __ATOMIC_RELAXED, __HIP_MEMORY_SCOPE_AGENT);
      int e1 = __hip_atomic_load(myep1, __ATOMIC_RELAXED, __HIP_MEMORY_SCOPE_AGENT);
      if (e0 >= t || e1 >= t) break;
    }
    asm volatile("" ::: "memory");      // no hoist of h loads above the wait

    // ---- forced burst, 4-phase drain: issue all 32 16B loads; MFMA 8 at a
    // time as loads retire. Split accumulators (a/b pairs) double chain ILP.
    const unsigned short* hr = hseq + (size_t)t * (NBLK * Bb * HIDB) + kg * 512 + arow * 8;
    short8 f[32];
#pragma unroll
    for (int kk = 0; kk < 32; kk++) f[kk] = *(const short8*)(hr + kk * 2048);

    f32x4 a0 = xa0, a1 = xa1;
    f32x4 b0 = {0.f,0.f,0.f,0.f}, b1 = {0.f,0.f,0.f,0.f};
    asm volatile("s_waitcnt vmcnt(24)" ::: "memory");   // f[0..7] landed
    __builtin_amdgcn_sched_barrier(0x187);
#pragma unroll
    for (int kk = 0; kk < 8; kk++) {
      a0 = __builtin_amdgcn_mfma_f32_16x16x32_bf16(f[kk], W0[(16 + kk) * 64 + ln], a0, 0, 0, 0);
      a1 = __builtin_amdgcn_mfma_f32_16x16x32_bf16(f[kk], W1[(16 + kk) * 64 + ln], a1, 0, 0, 0);
    }
    asm volatile("s_waitcnt vmcnt(16)" ::: "memory");   // f[8..15]
    __builtin_amdgcn_sched_barrier(0x187);
#pragma unroll
    for (int kk = 8; kk < 16; kk++) {
      a0 = __builtin_amdgcn_mfma_f32_16x16x32_bf16(f[kk], W0[(16 + kk) * 64 + ln], a0, 0, 0, 0);
      a1 = __builtin_amdgcn_mfma_f32_16x16x32_bf16(f[kk], W1[(16 + kk) * 64 + ln], a1, 0, 0, 0);
    }
    asm volatile("s_waitcnt vmcnt(8)" ::: "memory");    // f[16..23]
    __builtin_amdgcn_sched_barrier(0x187);
#pragma unroll
    for (int kk = 16; kk < 24; kk++) {
      b0 = __builtin_amdgcn_mfma_f32_16x16x32_bf16(f[kk], W0[(16 + kk) * 64 + ln], b0, 0, 0, 0);
      b1 = __builtin_amdgcn_mfma_f32_16x16x32_bf16(f[kk], W1[(16 + kk) * 64 + ln], b1, 0, 0, 0);
    }
    asm volatile("s_waitcnt vmcnt(0)" ::: "memory");    // f[24..31]
    __builtin_amdgcn_sched_barrier(0x187);
#pragma unroll
    for (int kk = 24; kk < 32; kk++) {
      b0 = __builtin_amdgcn_mfma_f32_16x16x32_bf16(f[kk], W0[(16 + kk) * 64 + ln], b0, 0, 0, 0);
      b1 = __builtin_amdgcn_mfma_f32_16x16x32_bf16(f[kk], W1[(16 + kk) * 64 + ln], b1, 0, 0, 0);
    }
    a0 += b0; a1 += b1;                 // join split chains

    if (t < Tt - 1) {
      // ---- cell update with INLINE pack+store: store for row-group r flies
      // while r+1's transcendental chain computes. vmcnt clean at entry
      // (burst fully drained above) -> exactly 4 store instrs outstanding.
      unsigned long long* hob = (unsigned long long*)hseq
                                + (size_t)(t + 1) * (NBLK * Bb * HIDB / 4)
                                + bc * (Bb * HIDB / 4);
#pragma unroll
      for (int r = 0; r < 4; r++) {
        const float p0 = a0[r], p1 = a1[r];
        const float s0 = __shfl_xor(p0, 8), s1 = __shfl_xor(p1, 8);
        const float gi = (lo ? p0 : s0) + bi;
        const float gj = (lo ? s0 : p0) + bj;
        const float gf = (lo ? p1 : s1) + bff;
        const float go = (lo ? s1 : p1) + bo;
        const float cn = cstate[r] * fsig(gf + 1.0f) + fsig(gi) * ftanhf(gj);
        cstate[r] = cn;
        const float hn = ftanhf(cn) * fsig(go);
        unsigned short us = f2bf(hn);
        unsigned short ps = (unsigned short)__shfl_xor((int)us, 1);
        unsigned int hw = (unsigned)us | ((unsigned)ps << 16);
        unsigned int p2 = (unsigned)__shfl_xor((int)hw, 2);
        unsigned long long hq = (unsigned long long)hw | ((unsigned long long)p2 << 32);
        if (lo && !(c & 3))
          __hip_atomic_store(hob + (rbase + r) * 2 + (c >> 2),
                             hq, __ATOMIC_RELAXED, __HIP_MEMORY_SCOPE_AGENT);
      }
      asm volatile("" ::: "memory");    // stores issued above this point
      // ---- x-loads for t+1 issued BEFORE the ack; counted drain acks only
      // the 4 stores (oldest), x-loads keep flying under the flag + x-GEMM.
      const unsigned short* xr = xT + ((size_t)(t + 1) * Bb + arow) * Ee + kg * 8;
      short8 xl[16];
#pragma unroll
      for (int kk = 0; kk < 16; kk++) xl[kk] = *(const short8*)(xr + kk * 32);
      asm volatile("s_waitcnt vmcnt(16)" ::: "memory"); // 4 stores acked
      __builtin_amdgcn_sched_barrier(0x187);
      if (ln == 0)
        __hip_atomic_store(myslot, t + 1, __ATOMIC_RELAXED, __HIP_MEMORY_SCOPE_AGENT);
      // x-part MFMAs for t+1 (W from registers) in the detect shadow
      {
        f32x4 c0 = {0.f,0.f,0.f,0.f}, c1 = {0.f,0.f,0.f,0.f};
#pragma unroll
        for (int kk = 0; kk < 16; kk++) {
          c0 = __builtin_amdgcn_mfma_f32_16x16x32_bf16(xl[kk], wx0[kk], c0, 0, 0, 0);
          c1 = __builtin_amdgcn_mfma_f32_16x16x32_bf16(xl[kk], wx1[kk], c1, 0, 0, 0);
        }
        xa0 = c0; xa1 = c1;
      }
    } else {
      float hnew[4];
#pragma unroll
      for (int r = 0; r < 4; r++) {
        const float p0 = a0[r], p1 = a1[r];
        const float s0 = __shfl_xor(p0, 8), s1 = __shfl_xor(p1, 8);
        const float gi = (lo ? p0 : s0) + bi;
        const float gj = (lo ? s0 : p0) + bj;
        const float gf = (lo ? p1 : s1) + bff;
        const float go = (lo ? s1 : p1) + bo;
        const float cn = cstate[r] * fsig(gf + 1.0f) + fsig(gi) * ftanhf(gj);
        cstate[r] = cn;
        hnew[r] = ftanhf(cn) * fsig(go);
      }
      if (lo) {
#pragma unroll
        for (int r = 0; r < 4; r++) h_f32[(rbase + r) * Hh + hid] = hnew[r];
      }
    }
  }
}

// ---- classifier: pred = h @ outW + outb, softmax, per-row CE --------------
__global__ __launch_bounds__(256) void classifier_kernel(
    const float* __restrict__ h, const float* __restrict__ outW,
    const float* __restrict__ outb, const float* __restrict__ y,
    float* __restrict__ out, float* __restrict__ losses) {
  __shared__ float red[256];
  const int brow = blockIdx.x;
  const int tid = threadIdx.x;
  const int cc = tid & 31;
  const int part = tid >> 5;
  const float* hr = h + brow * Hh;
  float p = 0.f;
  for (int k = part * 128; k < part * 128 + 128; k++)
    p += hr[k] * outW[k * Cc + cc];
  red[tid] = p;
  __syncthreads();
  if (part < 4) red[tid] += red[tid + 128];
  __syncthreads();
  if (part < 2) red[tid] += red[tid + 64];
  __syncthreads();
  if (part < 1) red[tid] += red[tid + 32];
  __syncthreads();
  if (tid < 32) {
    const float logit = red[tid] + outb[tid];
    float m = logit;
    for (int off = 16; off >= 1; off >>= 1) m = fmaxf(m, __shfl_xor(m, off));
    const float e = __expf(logit - m);
    float s = e;
    for (int off = 16; off >= 1; off >>= 1) s += __shfl_xor(s, off);
    out[brow * Cc + tid] = logit;
    out[Bb * Cc + brow * Cc + tid] = e / s;
    const float logp = (logit - m) - __logf(s);
    float contrib = y[brow * Cc + tid] * logp;
    for (int off = 16; off >= 1; off >>= 1) contrib += __shfl_xor(contrib, off);
    if (tid == 0) losses[brow] = -contrib;
  }
}

__global__ __launch_bounds__(64) void finalize_kernel(const float* __restrict__ losses,
                                                      float* __restrict__ out) {
  float v = losses[threadIdx.x];
  for (int off = 32; off >= 1; off >>= 1) v += __shfl_down(v, off);
  if (threadIdx.x == 0) out[2 * Bb * Cc] = v * (1.0f / Bb);
}

extern "C" void kernel_launch(void* const* d_in, const int* in_sizes, int n_in,
                              void* d_out, int out_size, void* d_ws, size_t ws_size,
                              hipStream_t stream) {
  const float* x    = (const float*)d_in[0];
  const float* y    = (const float*)d_in[1];
  // d_in[2] = seqlen (unused)
  const float* W    = (const float*)d_in[3];
  const float* bias = (const float*)d_in[4];
  const float* outW = (const float*)d_in[5];
  const float* outb = (const float*)d_in[6];
  float* out = (float*)d_out;

  char* wsp = (char*)d_ws;
  size_t off = 0;
  auto walloc = [&](size_t bytes) -> void* {
    void* p = wsp + off;
    off += (bytes + 255) & ~(size_t)255;
    return p;
  };
  unsigned short* xT   = (unsigned short*)walloc((size_t)Bb * Tt * Ee * 2);         // 32 MiB
  unsigned short* Wpk  = (unsigned short*)walloc((size_t)NBLK * 2 * NKS * 64 * 16); // 12 MiB
  unsigned short* hseq = (unsigned short*)walloc((size_t)Tt * Bb * Hh * 2);         // 64 MiB rotating h
  float* hf     = (float*)walloc((size_t)Bb * Hh * 4);
  float* losses = (float*)walloc(256);
  int* flg      = (int*)walloc((4 * NBLK * FPAD + 4 * NREP * FPAD) * 4);            // flags + epochs
  (void)ws_size; (void)in_sizes; (void)n_in; (void)out_size;

  transpose_x_kernel<<<Bb * Tt, 256, 0, stream>>>(x, xT);
  pack_w_kernel<<<NBLK * 2 * NKS, 64, 0, stream>>>(W, Wpk);
  init_state_kernel<<<(Bb * Hh) / 256, 256, 0, stream>>>(hseq, flg);

  lstm_persist<<<NBLK + 2, 256, 0, stream>>>(xT, Wpk, bias, hseq, hf, flg);

  classifier_kernel<<<Bb, 256, 0, stream>>>(hf, outW, outb, y, out, losses);
  finalize_kernel<<<1, 64, 0, stream>>>(losses, out);
}